// Round 12
// baseline (269.278 us; speedup 1.0000x reference)
//
#include <hip/hip_runtime.h>
#include <math.h>

#define N_NODES 50000
#define N_EDGES 800000
#define DIM 64
#define HID 128
#define LAYERS 3
#define NGRAPH 128

#define SCAN_TILE 1024
#define SCAN_NB ((N_NODES + SCAN_TILE - 1) / SCAN_TILE)   // 49

#define POOL_ROWS 256
#define POOL_NB ((N_NODES + POOL_ROWS - 1) / POOL_ROWS)   // 196

typedef __attribute__((ext_vector_type(8))) short short8v;   // 8 bf16 (4 VGPR)
typedef __attribute__((ext_vector_type(4))) float f32x4;

__device__ __forceinline__ float bf2f(unsigned short u) {
    return __uint_as_float(((unsigned)u) << 16);
}
__device__ __forceinline__ unsigned short f2bf(float x) {
    unsigned u = __float_as_uint(x);
    unsigned r = (u + 0x7fff + ((u >> 16) & 1)) >> 16;   // RNE
    return (unsigned short)r;
}
// fast tanh: 1 - 2/(1+e^{2x}), clamp |x|<=9; err ~1e-6 << bf16 rounding
__device__ __forceinline__ float fast_tanh(float x) {
    float xc = fminf(fmaxf(x, -9.0f), 9.0f);
    float y = __expf(2.0f * xc);
    return 1.0f - 2.0f * __builtin_amdgcn_rcpf(y + 1.0f);
}

// ---------------------------------------------------------------------------
// CSR build. count records each edge's rank (atomicAdd return, u16: degree
// << 65536) so place needs no atomic. csr entries u16 (src < 65536).
// ---------------------------------------------------------------------------
__global__ void count_kernel(const int* __restrict__ dst,
                             int* __restrict__ counts,
                             unsigned short* __restrict__ rank) {
    int e = blockIdx.x * blockDim.x + threadIdx.x;
    if (e >= N_EDGES) return;
    rank[e] = (unsigned short)atomicAdd(&counts[dst[e]], 1);
}

__global__ void scan_partial_kernel(const int* __restrict__ counts,
                                    int* __restrict__ bsum) {
    __shared__ int red[256];
    const int b = blockIdx.x, tid = threadIdx.x;
    const int base = b * SCAN_TILE + tid * 4;
    int s = 0;
    if (base + 3 < N_NODES) {
        int4 v = *reinterpret_cast<const int4*>(counts + base);
        s = v.x + v.y + v.z + v.w;
    } else {
        for (int i = 0; i < 4; ++i)
            if (base + i < N_NODES) s += counts[base + i];
    }
    red[tid] = s;
    __syncthreads();
    for (int off = 128; off > 0; off >>= 1) {
        if (tid < off) red[tid] += red[tid + off];
        __syncthreads();
    }
    if (tid == 0) bsum[b] = red[0];
}

__global__ void scan_mid_kernel(const int* __restrict__ bsum,
                                int* __restrict__ bpre,
                                int* __restrict__ offsets) {
    int tid = threadIdx.x;   // 64 threads, one wave
    int orig = (tid < SCAN_NB) ? bsum[tid] : 0;
    int v = orig;
    for (int off = 1; off < 64; off <<= 1) {
        int u = __shfl_up(v, off);
        if (tid >= off) v += u;
    }
    if (tid < SCAN_NB) bpre[tid] = v - orig;
    if (tid == 0) offsets[N_NODES] = N_EDGES;
}

__global__ void scan_final_kernel(const int* __restrict__ counts,
                                  const int* __restrict__ bpre,
                                  int* __restrict__ offsets) {
    __shared__ int pre[256];
    const int b = blockIdx.x, tid = threadIdx.x;
    const int base = b * SCAN_TILE + tid * 4;
    int c[4];
    int s = 0;
#pragma unroll
    for (int i = 0; i < 4; ++i) {
        c[i] = (base + i < N_NODES) ? counts[base + i] : 0;
        s += c[i];
    }
    pre[tid] = s;
    __syncthreads();
    for (int off = 1; off < 256; off <<= 1) {
        int v = (tid >= off) ? pre[tid - off] : 0;
        __syncthreads();
        pre[tid] += v;
        __syncthreads();
    }
    int run = bpre[b] + pre[tid] - s;
#pragma unroll
    for (int i = 0; i < 4; ++i) {
        if (base + i < N_NODES) {
            offsets[base + i] = run;
            run += c[i];
        }
    }
}

__global__ void place_kernel(const int* __restrict__ src,
                             const int* __restrict__ dst,
                             const unsigned short* __restrict__ rank,
                             const int* __restrict__ offsets,
                             unsigned short* __restrict__ csr_src) {
    int e = blockIdx.x * blockDim.x + threadIdx.x;
    if (e >= N_EDGES) return;
    csr_src[offsets[dst[e]] + (int)rank[e]] = (unsigned short)src[e];
}

// ---------------------------------------------------------------------------
// weight repack: W[L][K][C] f32 -> frag-major bf16 P[L][KT][CT][64 lanes][8]
// lane l (li=l&15, hi=l>>4) gets W[kt*32 + hi*8 + j][ct*16 + li], j=0..7
// ---------------------------------------------------------------------------
template<int K, int C>
__global__ void repack_kernel(const float* __restrict__ W, unsigned short* __restrict__ P) {
    constexpr int KT = K / 32, CT = C / 16;
    int t = blockIdx.x * 256 + threadIdx.x;
    if (t >= LAYERS * KT * CT * 64) return;
    int lane = t & 63; int rest = t >> 6;
    int ct = rest % CT; rest /= CT;
    int kt = rest % KT; int l = rest / KT;
    int li = lane & 15, hi = lane >> 4;
    const float* Wl = W + (size_t)l * K * C;
    short8v o;
#pragma unroll
    for (int j = 0; j < 8; ++j)
        o[j] = (short)f2bf(Wl[(size_t)(kt * 32 + hi * 8 + j) * C + ct * 16 + li]);
    *reinterpret_cast<short8v*>(P + ((size_t)l * KT * CT * 64 + (size_t)(kt * CT + ct) * 64 + lane) * 8) = o;
}

// ---------------------------------------------------------------------------
// fused GIN layer with LOAD-BALANCED gather (round-12): the block's 16 rows
// own a contiguous CSR range; it is split EVENLY across the 16 thread-groups
// (Poisson-degree max no longer gates the walk). Register accumulate; flush
// to a padded f32 LDS tile via ds f32 atomics at (rare) row crossings.
// Then MFMA W1 -> tanh -> xpose -> W2 -> tanh -> xpose -> W3 -> tanh(tanh).
// IN/OUT ping-pong (round-6 race). Frag conv: k = kt*32+hi*8+j, row/col=li.
// D conv (m89): col=li, row=hi*4+j. tileA/B swizzle byte^=(row&7)<<4.
// aggF stride 68 floats -> 2-way banks (free).
// ---------------------------------------------------------------------------
template<bool F32IN>
__global__ __launch_bounds__(256) void gnn_layer_kernel(
        const float* __restrict__ xf, const unsigned short* __restrict__ xb,
        const int* __restrict__ offsets, const unsigned short* __restrict__ csr_src,
        const unsigned short* __restrict__ pw1, const float* __restrict__ bias1,
        const unsigned short* __restrict__ pw2, const float* __restrict__ bias2,
        const unsigned short* __restrict__ pw3, const float* __restrict__ bias3,
        unsigned short* __restrict__ outx) {
    __shared__ float aggF[16 * 68];              // 4.25 KB, padded stride
    __shared__ unsigned short tileA[16 * 128];   // 4 KB
    __shared__ unsigned short tileB[16 * 128];   // 4 KB
    __shared__ int soff[17];
    const int tid = threadIdx.x;
    const int wave = tid >> 6, lane = tid & 63;
    const int li = lane & 15, hi = lane >> 4;
    const int r0 = blockIdx.x * 16;              // 3125*16 == N exactly
    char* tA = reinterpret_cast<char*>(tileA);
    char* tB = reinterpret_cast<char*>(tileB);

    if (tid < 17) soff[tid] = offsets[r0 + tid];

    // ---- self contribution: thread (nr,q) seeds aggF[nr][q*4..+3] ----
    {
        const int nr = tid >> 4, q = tid & 15;
        const int n = r0 + nr;
        float v0, v1, v2, v3;
        if (F32IN) {
            float4 v = *reinterpret_cast<const float4*>(xf + (size_t)n * DIM + q * 4);
            v0 = v.x; v1 = v.y; v2 = v.z; v3 = v.w;
        } else {
            ushort4 u = *reinterpret_cast<const ushort4*>(xb + (size_t)n * DIM + q * 4);
            v0 = bf2f(u.x); v1 = bf2f(u.y); v2 = bf2f(u.z); v3 = bf2f(u.w);
        }
        float* d = &aggF[nr * 68 + q * 4];
        d[0] = v0; d[1] = v1; d[2] = v2; d[3] = v3;
    }
    __syncthreads();

    // ---- balanced edge walk: group g takes an even slice of the block's
    //      CSR range; lane q owns channels q*4..q*4+3 ----
    {
        const int g = tid >> 4, q = tid & 15;
        const int pb = soff[0];
        const int pend = soff[16];
        const int m = pend - pb;
        const int chunk = (m + 15) >> 4;
        int p = pb + g * chunk;
        const int pe = min(p + chunk, pend);
        if (p < pe) {
            int row = 0;
            while (soff[row + 1] <= p) ++row;    // group-uniform, <=16 iters
            int next = soff[row + 1];
            float a0 = 0.f, a1 = 0.f, a2 = 0.f, a3 = 0.f;
            while (p < pe) {
                if (p >= next) {
                    float* d = &aggF[row * 68 + q * 4];
                    atomicAdd(d + 0, a0); atomicAdd(d + 1, a1);
                    atomicAdd(d + 2, a2); atomicAdd(d + 3, a3);
                    a0 = a1 = a2 = a3 = 0.f;
                    do { ++row; next = soff[row + 1]; } while (p >= next);
                }
                const int lim = min(pe, next);
                // unroll-4: 4 independent row loads in flight
                for (; p + 4 <= lim; p += 4) {
                    int s0 = csr_src[p + 0];
                    int s1 = csr_src[p + 1];
                    int s2 = csr_src[p + 2];
                    int s3 = csr_src[p + 3];
                    if (F32IN) {
                        float4 v0 = *reinterpret_cast<const float4*>(xf + (size_t)s0 * DIM + q * 4);
                        float4 v1 = *reinterpret_cast<const float4*>(xf + (size_t)s1 * DIM + q * 4);
                        float4 v2 = *reinterpret_cast<const float4*>(xf + (size_t)s2 * DIM + q * 4);
                        float4 v3 = *reinterpret_cast<const float4*>(xf + (size_t)s3 * DIM + q * 4);
                        a0 += v0.x + v1.x + v2.x + v3.x;
                        a1 += v0.y + v1.y + v2.y + v3.y;
                        a2 += v0.z + v1.z + v2.z + v3.z;
                        a3 += v0.w + v1.w + v2.w + v3.w;
                    } else {
                        ushort4 v0 = *reinterpret_cast<const ushort4*>(xb + (size_t)s0 * DIM + q * 4);
                        ushort4 v1 = *reinterpret_cast<const ushort4*>(xb + (size_t)s1 * DIM + q * 4);
                        ushort4 v2 = *reinterpret_cast<const ushort4*>(xb + (size_t)s2 * DIM + q * 4);
                        ushort4 v3 = *reinterpret_cast<const ushort4*>(xb + (size_t)s3 * DIM + q * 4);
                        a0 += bf2f(v0.x) + bf2f(v1.x) + bf2f(v2.x) + bf2f(v3.x);
                        a1 += bf2f(v0.y) + bf2f(v1.y) + bf2f(v2.y) + bf2f(v3.y);
                        a2 += bf2f(v0.z) + bf2f(v1.z) + bf2f(v2.z) + bf2f(v3.z);
                        a3 += bf2f(v0.w) + bf2f(v1.w) + bf2f(v2.w) + bf2f(v3.w);
                    }
                }
                for (; p < lim; ++p) {
                    int s = csr_src[p];
                    if (F32IN) {
                        float4 v = *reinterpret_cast<const float4*>(xf + (size_t)s * DIM + q * 4);
                        a0 += v.x; a1 += v.y; a2 += v.z; a3 += v.w;
                    } else {
                        ushort4 v = *reinterpret_cast<const ushort4*>(xb + (size_t)s * DIM + q * 4);
                        a0 += bf2f(v.x); a1 += bf2f(v.y); a2 += bf2f(v.z); a3 += bf2f(v.w);
                    }
                }
            }
            float* d = &aggF[row * 68 + q * 4];
            atomicAdd(d + 0, a0); atomicAdd(d + 1, a1);
            atomicAdd(d + 2, a2); atomicAdd(d + 3, a3);
        }
    }
    __syncthreads();

    // ---- A-frags from f32 agg tile (row = li, k = kt*32 + hi*8 + j) ----
    short8v af[2];
#pragma unroll
    for (int kt = 0; kt < 2; ++kt) {
        const float* s = &aggF[li * 68 + kt * 32 + hi * 8];
#pragma unroll
        for (int j = 0; j < 8; ++j) af[kt][j] = (short)f2bf(s[j]);
    }

    // ---- gemm1: K=64, C=128; wave owns ct = 2*wave + {0,1} ----
    f32x4 acc1[2];
#pragma unroll
    for (int c = 0; c < 2; ++c) acc1[c] = (f32x4){0.f, 0.f, 0.f, 0.f};
#pragma unroll
    for (int c = 0; c < 2; ++c) {
        const int ct = 2 * wave + c;
#pragma unroll
        for (int kt = 0; kt < 2; ++kt) {
            short8v bfr = *reinterpret_cast<const short8v*>(pw1 + ((size_t)(kt * 8 + ct) * 64 + lane) * 8);
            acc1[c] = __builtin_amdgcn_mfma_f32_16x16x32_bf16(af[kt], bfr, acc1[c], 0, 0, 0);
        }
    }
#pragma unroll
    for (int c = 0; c < 2; ++c) {
        const int ct = 2 * wave + c;
        float bv = bias1[ct * 16 + li];
#pragma unroll
        for (int j = 0; j < 4; ++j) {
            int row = hi * 4 + j;
            unsigned off = (unsigned)(row * 256 + (ct * 16 + li) * 2) ^ ((unsigned)(row & 7) << 4);
            *reinterpret_cast<unsigned short*>(tA + off) = f2bf(fast_tanh(acc1[c][j] + bv));
        }
    }
    __syncthreads();

    // ---- gemm2: K=128, C=128 ----
    short8v af2[4];
#pragma unroll
    for (int kt = 0; kt < 4; ++kt) {
        unsigned off = (unsigned)(li * 256 + (kt * 32 + hi * 8) * 2) ^ ((unsigned)(li & 7) << 4);
        af2[kt] = *reinterpret_cast<const short8v*>(tA + off);
    }
    f32x4 acc2[2];
#pragma unroll
    for (int c = 0; c < 2; ++c) acc2[c] = (f32x4){0.f, 0.f, 0.f, 0.f};
#pragma unroll
    for (int c = 0; c < 2; ++c) {
        const int ct = 2 * wave + c;
#pragma unroll
        for (int kt = 0; kt < 4; ++kt) {
            short8v bfr = *reinterpret_cast<const short8v*>(pw2 + ((size_t)(kt * 8 + ct) * 64 + lane) * 8);
            acc2[c] = __builtin_amdgcn_mfma_f32_16x16x32_bf16(af2[kt], bfr, acc2[c], 0, 0, 0);
        }
    }
#pragma unroll
    for (int c = 0; c < 2; ++c) {
        const int ct = 2 * wave + c;
        float bv = bias2[ct * 16 + li];
#pragma unroll
        for (int j = 0; j < 4; ++j) {
            int row = hi * 4 + j;
            unsigned off = (unsigned)(row * 256 + (ct * 16 + li) * 2) ^ ((unsigned)(row & 7) << 4);
            *reinterpret_cast<unsigned short*>(tB + off) = f2bf(fast_tanh(acc2[c][j] + bv));
        }
    }
    __syncthreads();

    // ---- gemm3: K=128, C=64; wave owns ct = wave ----
    short8v af3[4];
#pragma unroll
    for (int kt = 0; kt < 4; ++kt) {
        unsigned off = (unsigned)(li * 256 + (kt * 32 + hi * 8) * 2) ^ ((unsigned)(li & 7) << 4);
        af3[kt] = *reinterpret_cast<const short8v*>(tB + off);
    }
    f32x4 acc3 = (f32x4){0.f, 0.f, 0.f, 0.f};
#pragma unroll
    for (int kt = 0; kt < 4; ++kt) {
        short8v bfr = *reinterpret_cast<const short8v*>(pw3 + ((size_t)(kt * 4 + wave) * 64 + lane) * 8);
        acc3 = __builtin_amdgcn_mfma_f32_16x16x32_bf16(af3[kt], bfr, acc3, 0, 0, 0);
    }
    {
        float bv = bias3[wave * 16 + li];
#pragma unroll
        for (int j = 0; j < 4; ++j) {
            int row = r0 + hi * 4 + j;
            float v = fast_tanh(fast_tanh(acc3[j] + bv));
            outx[(size_t)row * DIM + wave * 16 + li] = f2bf(v);
        }
    }
}

// ---------------------------------------------------------------------------
// mean pool (node-parallel, bf16 input) + finalize
// ---------------------------------------------------------------------------
__global__ void pool_partial_kernel(const unsigned short* __restrict__ x,
                                    const int* __restrict__ batch,
                                    float* __restrict__ sums) {
    const int tid = threadIdx.x;
    const int d = tid & 63;
    const int rg = tid >> 6;
    int row = blockIdx.x * POOL_ROWS + rg;
    const int rowend = min(N_NODES, (blockIdx.x + 1) * POOL_ROWS);
    float acc = 0.f;
    int cur = -1;
    for (; row < rowend; row += 4) {
        int g = batch[row];
        if (g != cur) {
            if (cur >= 0) atomicAdd(&sums[cur * DIM + d], acc);
            acc = 0.f;
            cur = g;
        }
        acc += bf2f(x[(size_t)row * DIM + d]);
    }
    if (cur >= 0) atomicAdd(&sums[cur * DIM + d], acc);
}

__global__ void pool_final_kernel(const float* __restrict__ sums,
                                  const int* __restrict__ batch,
                                  float* __restrict__ out) {
    const int g = blockIdx.x;
    const int d = threadIdx.x;
    int lo = 0, hi = N_NODES;
    while (lo < hi) { int m = (lo + hi) >> 1; if (batch[m] < g) lo = m + 1; else hi = m; }
    int start = lo;
    hi = N_NODES;
    while (lo < hi) { int m = (lo + hi) >> 1; if (batch[m] < g + 1) lo = m + 1; else hi = m; }
    float cnt = (float)(lo - start);
    out[g * DIM + d] = sums[g * DIM + d] / fmaxf(cnt, 1.f);
}

// ---------------------------------------------------------------------------
extern "C" void kernel_launch(void* const* d_in, const int* in_sizes, int n_in,
                              void* d_out, int out_size, void* d_ws, size_t ws_size,
                              hipStream_t stream) {
    const float* attrs = (const float*)d_in[0];
    const float* W1    = (const float*)d_in[1];
    const float* b1    = (const float*)d_in[2];
    const float* W2    = (const float*)d_in[3];
    const float* b2    = (const float*)d_in[4];
    const float* W3    = (const float*)d_in[5];
    const float* b3    = (const float*)d_in[6];
    const int* edge_index = (const int*)d_in[7];
    const int* batch      = (const int*)d_in[8];
    float* out = (float*)d_out;

    unsigned short* buf0 = (unsigned short*)d_ws;               // N*64 bf16
    unsigned short* buf1 = buf0 + (size_t)N_NODES * DIM;        // N*64 bf16
    unsigned short* pW1  = buf1 + (size_t)N_NODES * DIM;        // 24576
    unsigned short* pW2  = pW1 + 24576;                         // 49152
    unsigned short* pW3  = pW2 + 49152;                         // 24576
    float* psums  = (float*)(pW3 + 24576);                      // G*64 f32
    int* offsets  = (int*)(psums + NGRAPH * DIM);               // N+1
    unsigned short* csr16 = (unsigned short*)(offsets + N_NODES + 1);  // E u16
    unsigned short* rank  = csr16 + N_EDGES;                    // E u16
    int* counts   = (int*)(rank + N_EDGES);                     // N
    int* bsum     = counts + N_NODES;                           // SCAN_NB
    int* bpre     = bsum + SCAN_NB;                             // SCAN_NB

    const int* src = edge_index;
    const int* dst = edge_index + N_EDGES;

    const int edge_blocks = (N_EDGES + 255) / 256;
    const int gnn_blocks  = N_NODES / 16;                       // 3125, exact

    // ---- CSR build (once; edge list is layer-invariant) ----
    hipMemsetAsync(counts, 0, (size_t)N_NODES * sizeof(int), stream);
    count_kernel<<<edge_blocks, 256, 0, stream>>>(dst, counts, rank);
    scan_partial_kernel<<<SCAN_NB, 256, 0, stream>>>(counts, bsum);
    scan_mid_kernel<<<1, 64, 0, stream>>>(bsum, bpre, offsets);
    scan_final_kernel<<<SCAN_NB, 256, 0, stream>>>(counts, bpre, offsets);
    place_kernel<<<edge_blocks, 256, 0, stream>>>(src, dst, rank, offsets, csr16);

    // ---- weight repack to frag-major bf16 (once) ----
    repack_kernel<DIM, HID><<<(LAYERS * 2 * 8 * 64 + 255) / 256, 256, 0, stream>>>(W1, pW1);
    repack_kernel<HID, HID><<<(LAYERS * 4 * 8 * 64 + 255) / 256, 256, 0, stream>>>(W2, pW2);
    repack_kernel<HID, DIM><<<(LAYERS * 4 * 4 * 64 + 255) / 256, 256, 0, stream>>>(W3, pW3);

    // ---- fused layers, ping-pong: attrs -> buf0 -> buf1 -> buf0 ----
    for (int l = 0; l < LAYERS; ++l) {
        const unsigned short* w1 = pW1 + (size_t)l * 2 * 8 * 64 * 8;
        const unsigned short* w2 = pW2 + (size_t)l * 4 * 8 * 64 * 8;
        const unsigned short* w3 = pW3 + (size_t)l * 4 * 4 * 64 * 8;
        const float* bb1 = b1 + (size_t)l * HID;
        const float* bb2 = b2 + (size_t)l * HID;
        const float* bb3 = b3 + (size_t)l * DIM;
        if (l == 0)
            gnn_layer_kernel<true><<<gnn_blocks, 256, 0, stream>>>(
                attrs, nullptr, offsets, csr16, w1, bb1, w2, bb2, w3, bb3, buf0);
        else {
            const unsigned short* in = (l == 1) ? buf0 : buf1;
            unsigned short* outb     = (l == 1) ? buf1 : buf0;
            gnn_layer_kernel<false><<<gnn_blocks, 256, 0, stream>>>(
                nullptr, in, offsets, csr16, w1, bb1, w2, bb2, w3, bb3, outb);
        }
    }

    // ---- mean pool (reads buf0 after layer 2) ----
    hipMemsetAsync(psums, 0, (size_t)NGRAPH * DIM * sizeof(float), stream);
    pool_partial_kernel<<<POOL_NB, 256, 0, stream>>>(buf0, batch, psums);
    pool_final_kernel<<<NGRAPH, DIM, 0, stream>>>(psums, batch, out);
}

// Round 13
// 186.720 us; speedup vs baseline: 1.4421x; 1.4421x over previous
//
#include <hip/hip_runtime.h>
#include <math.h>

#define N_NODES 50000
#define N_EDGES 800000
#define DIM 64
#define HID 128
#define LAYERS 3
#define NGRAPH 128

#define SCAN_TILE 1024
#define SCAN_NB ((N_NODES + SCAN_TILE - 1) / SCAN_TILE)   // 49

#define POOL_ROWS 256
#define POOL_NB ((N_NODES + POOL_ROWS - 1) / POOL_ROWS)   // 196

typedef __attribute__((ext_vector_type(8))) short short8v;   // 8 bf16 (4 VGPR)
typedef __attribute__((ext_vector_type(4))) float f32x4;

__device__ __forceinline__ float bf2f(unsigned short u) {
    return __uint_as_float(((unsigned)u) << 16);
}
__device__ __forceinline__ unsigned short f2bf(float x) {
    unsigned u = __float_as_uint(x);
    unsigned r = (u + 0x7fff + ((u >> 16) & 1)) >> 16;   // RNE
    return (unsigned short)r;
}
// fast tanh: 1 - 2/(1+e^{2x}), clamp |x|<=9; err ~1e-6 << bf16 rounding
__device__ __forceinline__ float fast_tanh(float x) {
    float xc = fminf(fmaxf(x, -9.0f), 9.0f);
    float y = __expf(2.0f * xc);
    return 1.0f - 2.0f * __builtin_amdgcn_rcpf(y + 1.0f);
}

// ---------------------------------------------------------------------------
// CSR build. count records each edge's rank (atomicAdd return, u16) so
// place needs no atomic. csr entries u16 (src < 65536).
// ---------------------------------------------------------------------------
__global__ void count_kernel(const int* __restrict__ dst,
                             int* __restrict__ counts,
                             unsigned short* __restrict__ rank) {
    int e = blockIdx.x * blockDim.x + threadIdx.x;
    if (e >= N_EDGES) return;
    rank[e] = (unsigned short)atomicAdd(&counts[dst[e]], 1);
}

__global__ void scan_partial_kernel(const int* __restrict__ counts,
                                    int* __restrict__ bsum) {
    __shared__ int red[256];
    const int b = blockIdx.x, tid = threadIdx.x;
    const int base = b * SCAN_TILE + tid * 4;
    int s = 0;
    if (base + 3 < N_NODES) {
        int4 v = *reinterpret_cast<const int4*>(counts + base);
        s = v.x + v.y + v.z + v.w;
    } else {
        for (int i = 0; i < 4; ++i)
            if (base + i < N_NODES) s += counts[base + i];
    }
    red[tid] = s;
    __syncthreads();
    for (int off = 128; off > 0; off >>= 1) {
        if (tid < off) red[tid] += red[tid + off];
        __syncthreads();
    }
    if (tid == 0) bsum[b] = red[0];
}

__global__ void scan_mid_kernel(const int* __restrict__ bsum,
                                int* __restrict__ bpre,
                                int* __restrict__ offsets) {
    int tid = threadIdx.x;   // 64 threads, one wave
    int orig = (tid < SCAN_NB) ? bsum[tid] : 0;
    int v = orig;
    for (int off = 1; off < 64; off <<= 1) {
        int u = __shfl_up(v, off);
        if (tid >= off) v += u;
    }
    if (tid < SCAN_NB) bpre[tid] = v - orig;
    if (tid == 0) offsets[N_NODES] = N_EDGES;
}

__global__ void scan_final_kernel(const int* __restrict__ counts,
                                  const int* __restrict__ bpre,
                                  int* __restrict__ offsets) {
    __shared__ int pre[256];
    const int b = blockIdx.x, tid = threadIdx.x;
    const int base = b * SCAN_TILE + tid * 4;
    int c[4];
    int s = 0;
#pragma unroll
    for (int i = 0; i < 4; ++i) {
        c[i] = (base + i < N_NODES) ? counts[base + i] : 0;
        s += c[i];
    }
    pre[tid] = s;
    __syncthreads();
    for (int off = 1; off < 256; off <<= 1) {
        int v = (tid >= off) ? pre[tid - off] : 0;
        __syncthreads();
        pre[tid] += v;
        __syncthreads();
    }
    int run = bpre[b] + pre[tid] - s;
#pragma unroll
    for (int i = 0; i < 4; ++i) {
        if (base + i < N_NODES) {
            offsets[base + i] = run;
            run += c[i];
        }
    }
}

__global__ void place_kernel(const int* __restrict__ src,
                             const int* __restrict__ dst,
                             const unsigned short* __restrict__ rank,
                             const int* __restrict__ offsets,
                             unsigned short* __restrict__ csr_src) {
    int e = blockIdx.x * blockDim.x + threadIdx.x;
    if (e >= N_EDGES) return;
    csr_src[offsets[dst[e]] + (int)rank[e]] = (unsigned short)src[e];
}

// ---------------------------------------------------------------------------
// weight repack: W[L][K][C] f32 -> frag-major bf16 P[L][KT][CT][64 lanes][8]
// lane l (li=l&15, hi=l>>4) gets W[kt*32 + hi*8 + j][ct*16 + li], j=0..7
// ---------------------------------------------------------------------------
template<int K, int C>
__global__ void repack_kernel(const float* __restrict__ W, unsigned short* __restrict__ P) {
    constexpr int KT = K / 32, CT = C / 16;
    int t = blockIdx.x * 256 + threadIdx.x;
    if (t >= LAYERS * KT * CT * 64) return;
    int lane = t & 63; int rest = t >> 6;
    int ct = rest % CT; rest /= CT;
    int kt = rest % KT; int l = rest / KT;
    int li = lane & 15, hi = lane >> 4;
    const float* Wl = W + (size_t)l * K * C;
    short8v o;
#pragma unroll
    for (int j = 0; j < 8; ++j)
        o[j] = (short)f2bf(Wl[(size_t)(kt * 32 + hi * 8 + j) * C + ct * 16 + li]);
    *reinterpret_cast<short8v*>(P + ((size_t)l * KT * CT * 64 + (size_t)(kt * CT + ct) * 64 + lane) * 8) = o;
}

// ---------------------------------------------------------------------------
// fused GIN layer (round-13 gather): per node, TWO groups of 8 lanes each
// walk a fixed static half of the node's edge list (flat unroll-4 loops --
// round-12's dynamic segmentation regressed). 16 B loads per lane per edge
// (half the requests of 8 B x 16 lanes). Halves accumulate into two separate
// f32 LDS tiles (no atomics); A-frag read sums them.
// Then MFMA W1 -> tanh -> xpose -> W2 -> tanh -> xpose -> W3 -> tanh(tanh).
// IN/OUT ping-pong (round-6 race). Frag conv: k = kt*32+hi*8+j, row/col=li.
// D conv (m89): col=li, row=hi*4+j. tileA/B swizzle byte^=(row&7)<<4.
// agg tiles stride 68 floats (17*4 -> 16B-aligned, 2-way banks = free).
// ---------------------------------------------------------------------------
template<bool F32IN>
__global__ __launch_bounds__(256) void gnn_layer_kernel(
        const float* __restrict__ xf, const unsigned short* __restrict__ xb,
        const int* __restrict__ offsets, const unsigned short* __restrict__ csr_src,
        const unsigned short* __restrict__ pw1, const float* __restrict__ bias1,
        const unsigned short* __restrict__ pw2, const float* __restrict__ bias2,
        const unsigned short* __restrict__ pw3, const float* __restrict__ bias3,
        unsigned short* __restrict__ outx) {
    __shared__ float aggA[16 * 68];              // 4.25 KB, half 0 (+self)
    __shared__ float aggB[16 * 68];              // 4.25 KB, half 1
    __shared__ unsigned short tileA[16 * 128];   // 4 KB
    __shared__ unsigned short tileB[16 * 128];   // 4 KB
    __shared__ int soff[17];
    const int tid = threadIdx.x;
    const int wave = tid >> 6, lane = tid & 63;
    const int li = lane & 15, hi = lane >> 4;
    const int r0 = blockIdx.x * 16;              // 3125*16 == N exactly
    char* tA = reinterpret_cast<char*>(tileA);
    char* tB = reinterpret_cast<char*>(tileB);

    if (tid < 17) soff[tid] = offsets[r0 + tid];
    __syncthreads();

    // ---- gather: group = 8 lanes; node nr = group>>1, half h = group&1 ----
    {
        const int g  = tid >> 3;                 // 0..31
        const int nr = g >> 1;                   // node row 0..15
        const int h  = g & 1;
        const int q  = tid & 7;                  // channel oct (8 ch, 16 B)
        const int n  = r0 + nr;
        float a[8];
        if (h == 0) {                            // seed with self row
            if (F32IN) {
                const float* xr = xf + (size_t)n * DIM + q * 8;
                float4 u = *reinterpret_cast<const float4*>(xr);
                float4 w = *reinterpret_cast<const float4*>(xr + 4);
                a[0]=u.x; a[1]=u.y; a[2]=u.z; a[3]=u.w;
                a[4]=w.x; a[5]=w.y; a[6]=w.z; a[7]=w.w;
            } else {
                short8v v = *reinterpret_cast<const short8v*>(xb + (size_t)n * DIM + q * 8);
#pragma unroll
                for (int j = 0; j < 8; ++j) a[j] = bf2f((unsigned short)v[j]);
            }
        } else {
#pragma unroll
            for (int j = 0; j < 8; ++j) a[j] = 0.f;
        }
        const int p0 = soff[nr], pe1 = soff[nr + 1];
        const int mid = p0 + ((pe1 - p0 + 1) >> 1);
        int p        = h ? mid : p0;
        const int pe = h ? pe1 : mid;
        // flat unroll-4: 4 independent 16 B row-loads in flight per lane
        for (; p + 4 <= pe; p += 4) {
            int s0 = csr_src[p + 0];
            int s1 = csr_src[p + 1];
            int s2 = csr_src[p + 2];
            int s3 = csr_src[p + 3];
            if (F32IN) {
                const float* x0 = xf + (size_t)s0 * DIM + q * 8;
                const float* x1 = xf + (size_t)s1 * DIM + q * 8;
                const float* x2 = xf + (size_t)s2 * DIM + q * 8;
                const float* x3 = xf + (size_t)s3 * DIM + q * 8;
                float4 u0 = *reinterpret_cast<const float4*>(x0);
                float4 w0 = *reinterpret_cast<const float4*>(x0 + 4);
                float4 u1 = *reinterpret_cast<const float4*>(x1);
                float4 w1 = *reinterpret_cast<const float4*>(x1 + 4);
                float4 u2 = *reinterpret_cast<const float4*>(x2);
                float4 w2 = *reinterpret_cast<const float4*>(x2 + 4);
                float4 u3 = *reinterpret_cast<const float4*>(x3);
                float4 w3 = *reinterpret_cast<const float4*>(x3 + 4);
                a[0] += u0.x + u1.x + u2.x + u3.x;
                a[1] += u0.y + u1.y + u2.y + u3.y;
                a[2] += u0.z + u1.z + u2.z + u3.z;
                a[3] += u0.w + u1.w + u2.w + u3.w;
                a[4] += w0.x + w1.x + w2.x + w3.x;
                a[5] += w0.y + w1.y + w2.y + w3.y;
                a[6] += w0.z + w1.z + w2.z + w3.z;
                a[7] += w0.w + w1.w + w2.w + w3.w;
            } else {
                short8v v0 = *reinterpret_cast<const short8v*>(xb + (size_t)s0 * DIM + q * 8);
                short8v v1 = *reinterpret_cast<const short8v*>(xb + (size_t)s1 * DIM + q * 8);
                short8v v2 = *reinterpret_cast<const short8v*>(xb + (size_t)s2 * DIM + q * 8);
                short8v v3 = *reinterpret_cast<const short8v*>(xb + (size_t)s3 * DIM + q * 8);
#pragma unroll
                for (int j = 0; j < 8; ++j)
                    a[j] += bf2f((unsigned short)v0[j]) + bf2f((unsigned short)v1[j])
                          + bf2f((unsigned short)v2[j]) + bf2f((unsigned short)v3[j]);
            }
        }
        for (; p < pe; ++p) {
            int s = csr_src[p];
            if (F32IN) {
                const float* xs = xf + (size_t)s * DIM + q * 8;
                float4 u = *reinterpret_cast<const float4*>(xs);
                float4 w = *reinterpret_cast<const float4*>(xs + 4);
                a[0] += u.x; a[1] += u.y; a[2] += u.z; a[3] += u.w;
                a[4] += w.x; a[5] += w.y; a[6] += w.z; a[7] += w.w;
            } else {
                short8v v = *reinterpret_cast<const short8v*>(xb + (size_t)s * DIM + q * 8);
#pragma unroll
                for (int j = 0; j < 8; ++j) a[j] += bf2f((unsigned short)v[j]);
            }
        }
        float* d = (h ? aggB : aggA) + nr * 68 + q * 8;
        *reinterpret_cast<f32x4*>(d)     = (f32x4){a[0], a[1], a[2], a[3]};
        *reinterpret_cast<f32x4*>(d + 4) = (f32x4){a[4], a[5], a[6], a[7]};
    }
    __syncthreads();

    // ---- A-frags: sum the two halves (row = li, k = kt*32 + hi*8 + j) ----
    short8v af[2];
#pragma unroll
    for (int kt = 0; kt < 2; ++kt) {
        const float* sA = &aggA[li * 68 + kt * 32 + hi * 8];
        const float* sB = &aggB[li * 68 + kt * 32 + hi * 8];
#pragma unroll
        for (int j = 0; j < 8; ++j) af[kt][j] = (short)f2bf(sA[j] + sB[j]);
    }

    // ---- gemm1: K=64, C=128; wave owns ct = 2*wave + {0,1} ----
    f32x4 acc1[2];
#pragma unroll
    for (int c = 0; c < 2; ++c) acc1[c] = (f32x4){0.f, 0.f, 0.f, 0.f};
#pragma unroll
    for (int c = 0; c < 2; ++c) {
        const int ct = 2 * wave + c;
#pragma unroll
        for (int kt = 0; kt < 2; ++kt) {
            short8v bfr = *reinterpret_cast<const short8v*>(pw1 + ((size_t)(kt * 8 + ct) * 64 + lane) * 8);
            acc1[c] = __builtin_amdgcn_mfma_f32_16x16x32_bf16(af[kt], bfr, acc1[c], 0, 0, 0);
        }
    }
#pragma unroll
    for (int c = 0; c < 2; ++c) {
        const int ct = 2 * wave + c;
        float bv = bias1[ct * 16 + li];
#pragma unroll
        for (int j = 0; j < 4; ++j) {
            int row = hi * 4 + j;
            unsigned off = (unsigned)(row * 256 + (ct * 16 + li) * 2) ^ ((unsigned)(row & 7) << 4);
            *reinterpret_cast<unsigned short*>(tA + off) = f2bf(fast_tanh(acc1[c][j] + bv));
        }
    }
    __syncthreads();

    // ---- gemm2: K=128, C=128 ----
    short8v af2[4];
#pragma unroll
    for (int kt = 0; kt < 4; ++kt) {
        unsigned off = (unsigned)(li * 256 + (kt * 32 + hi * 8) * 2) ^ ((unsigned)(li & 7) << 4);
        af2[kt] = *reinterpret_cast<const short8v*>(tA + off);
    }
    f32x4 acc2[2];
#pragma unroll
    for (int c = 0; c < 2; ++c) acc2[c] = (f32x4){0.f, 0.f, 0.f, 0.f};
#pragma unroll
    for (int c = 0; c < 2; ++c) {
        const int ct = 2 * wave + c;
#pragma unroll
        for (int kt = 0; kt < 4; ++kt) {
            short8v bfr = *reinterpret_cast<const short8v*>(pw2 + ((size_t)(kt * 8 + ct) * 64 + lane) * 8);
            acc2[c] = __builtin_amdgcn_mfma_f32_16x16x32_bf16(af2[kt], bfr, acc2[c], 0, 0, 0);
        }
    }
#pragma unroll
    for (int c = 0; c < 2; ++c) {
        const int ct = 2 * wave + c;
        float bv = bias2[ct * 16 + li];
#pragma unroll
        for (int j = 0; j < 4; ++j) {
            int row = hi * 4 + j;
            unsigned off = (unsigned)(row * 256 + (ct * 16 + li) * 2) ^ ((unsigned)(row & 7) << 4);
            *reinterpret_cast<unsigned short*>(tB + off) = f2bf(fast_tanh(acc2[c][j] + bv));
        }
    }
    __syncthreads();

    // ---- gemm3: K=128, C=64; wave owns ct = wave ----
    short8v af3[4];
#pragma unroll
    for (int kt = 0; kt < 4; ++kt) {
        unsigned off = (unsigned)(li * 256 + (kt * 32 + hi * 8) * 2) ^ ((unsigned)(li & 7) << 4);
        af3[kt] = *reinterpret_cast<const short8v*>(tB + off);
    }
    f32x4 acc3 = (f32x4){0.f, 0.f, 0.f, 0.f};
#pragma unroll
    for (int kt = 0; kt < 4; ++kt) {
        short8v bfr = *reinterpret_cast<const short8v*>(pw3 + ((size_t)(kt * 4 + wave) * 64 + lane) * 8);
        acc3 = __builtin_amdgcn_mfma_f32_16x16x32_bf16(af3[kt], bfr, acc3, 0, 0, 0);
    }
    {
        float bv = bias3[wave * 16 + li];
#pragma unroll
        for (int j = 0; j < 4; ++j) {
            int row = r0 + hi * 4 + j;
            float v = fast_tanh(fast_tanh(acc3[j] + bv));
            outx[(size_t)row * DIM + wave * 16 + li] = f2bf(v);
        }
    }
}

// ---------------------------------------------------------------------------
// mean pool (node-parallel, bf16 input) + finalize
// ---------------------------------------------------------------------------
__global__ void pool_partial_kernel(const unsigned short* __restrict__ x,
                                    const int* __restrict__ batch,
                                    float* __restrict__ sums) {
    const int tid = threadIdx.x;
    const int d = tid & 63;
    const int rg = tid >> 6;
    int row = blockIdx.x * POOL_ROWS + rg;
    const int rowend = min(N_NODES, (blockIdx.x + 1) * POOL_ROWS);
    float acc = 0.f;
    int cur = -1;
    for (; row < rowend; row += 4) {
        int g = batch[row];
        if (g != cur) {
            if (cur >= 0) atomicAdd(&sums[cur * DIM + d], acc);
            acc = 0.f;
            cur = g;
        }
        acc += bf2f(x[(size_t)row * DIM + d]);
    }
    if (cur >= 0) atomicAdd(&sums[cur * DIM + d], acc);
}

__global__ void pool_final_kernel(const float* __restrict__ sums,
                                  const int* __restrict__ batch,
                                  float* __restrict__ out) {
    const int g = blockIdx.x;
    const int d = threadIdx.x;
    int lo = 0, hi = N_NODES;
    while (lo < hi) { int m = (lo + hi) >> 1; if (batch[m] < g) lo = m + 1; else hi = m; }
    int start = lo;
    hi = N_NODES;
    while (lo < hi) { int m = (lo + hi) >> 1; if (batch[m] < g + 1) lo = m + 1; else hi = m; }
    float cnt = (float)(lo - start);
    out[g * DIM + d] = sums[g * DIM + d] / fmaxf(cnt, 1.f);
}

// ---------------------------------------------------------------------------
extern "C" void kernel_launch(void* const* d_in, const int* in_sizes, int n_in,
                              void* d_out, int out_size, void* d_ws, size_t ws_size,
                              hipStream_t stream) {
    const float* attrs = (const float*)d_in[0];
    const float* W1    = (const float*)d_in[1];
    const float* b1    = (const float*)d_in[2];
    const float* W2    = (const float*)d_in[3];
    const float* b2    = (const float*)d_in[4];
    const float* W3    = (const float*)d_in[5];
    const float* b3    = (const float*)d_in[6];
    const int* edge_index = (const int*)d_in[7];
    const int* batch      = (const int*)d_in[8];
    float* out = (float*)d_out;

    unsigned short* buf0 = (unsigned short*)d_ws;               // N*64 bf16
    unsigned short* buf1 = buf0 + (size_t)N_NODES * DIM;        // N*64 bf16
    unsigned short* pW1  = buf1 + (size_t)N_NODES * DIM;        // 24576
    unsigned short* pW2  = pW1 + 24576;                         // 49152
    unsigned short* pW3  = pW2 + 49152;                         // 24576
    float* psums  = (float*)(pW3 + 24576);                      // G*64 f32
    int* offsets  = (int*)(psums + NGRAPH * DIM);               // N+1
    unsigned short* csr16 = (unsigned short*)(offsets + N_NODES + 1);  // E u16
    unsigned short* rank  = csr16 + N_EDGES;                    // E u16
    int* counts   = (int*)(rank + N_EDGES);                     // N
    int* bsum     = counts + N_NODES;                           // SCAN_NB
    int* bpre     = bsum + SCAN_NB;                             // SCAN_NB

    const int* src = edge_index;
    const int* dst = edge_index + N_EDGES;

    const int edge_blocks = (N_EDGES + 255) / 256;
    const int gnn_blocks  = N_NODES / 16;                       // 3125, exact

    // ---- CSR build (once; edge list is layer-invariant) ----
    hipMemsetAsync(counts, 0, (size_t)N_NODES * sizeof(int), stream);
    count_kernel<<<edge_blocks, 256, 0, stream>>>(dst, counts, rank);
    scan_partial_kernel<<<SCAN_NB, 256, 0, stream>>>(counts, bsum);
    scan_mid_kernel<<<1, 64, 0, stream>>>(bsum, bpre, offsets);
    scan_final_kernel<<<SCAN_NB, 256, 0, stream>>>(counts, bpre, offsets);
    place_kernel<<<edge_blocks, 256, 0, stream>>>(src, dst, rank, offsets, csr16);

    // ---- weight repack to frag-major bf16 (once) ----
    repack_kernel<DIM, HID><<<(LAYERS * 2 * 8 * 64 + 255) / 256, 256, 0, stream>>>(W1, pW1);
    repack_kernel<HID, HID><<<(LAYERS * 4 * 8 * 64 + 255) / 256, 256, 0, stream>>>(W2, pW2);
    repack_kernel<HID, DIM><<<(LAYERS * 4 * 4 * 64 + 255) / 256, 256, 0, stream>>>(W3, pW3);

    // ---- fused layers, ping-pong: attrs -> buf0 -> buf1 -> buf0 ----
    for (int l = 0; l < LAYERS; ++l) {
        const unsigned short* w1 = pW1 + (size_t)l * 2 * 8 * 64 * 8;
        const unsigned short* w2 = pW2 + (size_t)l * 4 * 8 * 64 * 8;
        const unsigned short* w3 = pW3 + (size_t)l * 4 * 4 * 64 * 8;
        const float* bb1 = b1 + (size_t)l * HID;
        const float* bb2 = b2 + (size_t)l * HID;
        const float* bb3 = b3 + (size_t)l * DIM;
        if (l == 0)
            gnn_layer_kernel<true><<<gnn_blocks, 256, 0, stream>>>(
                attrs, nullptr, offsets, csr16, w1, bb1, w2, bb2, w3, bb3, buf0);
        else {
            const unsigned short* in = (l == 1) ? buf0 : buf1;
            unsigned short* outb     = (l == 1) ? buf1 : buf0;
            gnn_layer_kernel<false><<<gnn_blocks, 256, 0, stream>>>(
                nullptr, in, offsets, csr16, w1, bb1, w2, bb2, w3, bb3, outb);
        }
    }

    // ---- mean pool (reads buf0 after layer 2) ----
    hipMemsetAsync(psums, 0, (size_t)NGRAPH * DIM * sizeof(float), stream);
    pool_partial_kernel<<<POOL_NB, 256, 0, stream>>>(buf0, batch, psums);
    pool_final_kernel<<<NGRAPH, DIM, 0, stream>>>(psums, batch, out);
}

// Round 14
// 183.384 us; speedup vs baseline: 1.4684x; 1.0182x over previous
//
#include <hip/hip_runtime.h>
#include <math.h>

#define N_NODES 50000
#define N_EDGES 800000
#define DIM 64
#define HID 128
#define LAYERS 3
#define NGRAPH 128

#define SCAN_TILE 1024
#define SCAN_NB ((N_NODES + SCAN_TILE - 1) / SCAN_TILE)   // 49

typedef __attribute__((ext_vector_type(8))) short short8v;   // 8 bf16 (4 VGPR)
typedef __attribute__((ext_vector_type(4))) float f32x4;

__device__ __forceinline__ float bf2f(unsigned short u) {
    return __uint_as_float(((unsigned)u) << 16);
}
__device__ __forceinline__ unsigned short f2bf(float x) {
    unsigned u = __float_as_uint(x);
    unsigned r = (u + 0x7fff + ((u >> 16) & 1)) >> 16;   // RNE
    return (unsigned short)r;
}
// fast tanh: 1 - 2/(1+e^{2x}), clamp |x|<=9; err ~1e-6 << bf16 rounding
__device__ __forceinline__ float fast_tanh(float x) {
    float xc = fminf(fmaxf(x, -9.0f), 9.0f);
    float y = __expf(2.0f * xc);
    return 1.0f - 2.0f * __builtin_amdgcn_rcpf(y + 1.0f);
}

// ---------------------------------------------------------------------------
// CSR build. count records each edge's rank (atomicAdd return, u16) so place
// needs no atomic; x2 unroll keeps two atomic round-trips in flight.
// csr entries u16 (src < 65536).
// ---------------------------------------------------------------------------
__global__ void count_kernel(const int* __restrict__ dst,
                             int* __restrict__ counts,
                             unsigned short* __restrict__ rank) {
    int e = (blockIdx.x * blockDim.x + threadIdx.x) * 2;
    if (e + 1 < N_EDGES) {
        int d0 = dst[e], d1 = dst[e + 1];
        int r0 = atomicAdd(&counts[d0], 1);      // independent; both in flight
        int r1 = atomicAdd(&counts[d1], 1);
        rank[e]     = (unsigned short)r0;
        rank[e + 1] = (unsigned short)r1;
    } else if (e < N_EDGES) {
        rank[e] = (unsigned short)atomicAdd(&counts[dst[e]], 1);
    }
}

__global__ void scan_partial_kernel(const int* __restrict__ counts,
                                    int* __restrict__ bsum) {
    __shared__ int red[256];
    const int b = blockIdx.x, tid = threadIdx.x;
    const int base = b * SCAN_TILE + tid * 4;
    int s = 0;
    if (base + 3 < N_NODES) {
        int4 v = *reinterpret_cast<const int4*>(counts + base);
        s = v.x + v.y + v.z + v.w;
    } else {
        for (int i = 0; i < 4; ++i)
            if (base + i < N_NODES) s += counts[base + i];
    }
    red[tid] = s;
    __syncthreads();
    for (int off = 128; off > 0; off >>= 1) {
        if (tid < off) red[tid] += red[tid + off];
        __syncthreads();
    }
    if (tid == 0) bsum[b] = red[0];
}

__global__ void scan_mid_kernel(const int* __restrict__ bsum,
                                int* __restrict__ bpre,
                                int* __restrict__ offsets) {
    int tid = threadIdx.x;   // 64 threads, one wave
    int orig = (tid < SCAN_NB) ? bsum[tid] : 0;
    int v = orig;
    for (int off = 1; off < 64; off <<= 1) {
        int u = __shfl_up(v, off);
        if (tid >= off) v += u;
    }
    if (tid < SCAN_NB) bpre[tid] = v - orig;
    if (tid == 0) offsets[N_NODES] = N_EDGES;
}

__global__ void scan_final_kernel(const int* __restrict__ counts,
                                  const int* __restrict__ bpre,
                                  int* __restrict__ offsets) {
    __shared__ int pre[256];
    const int b = blockIdx.x, tid = threadIdx.x;
    const int base = b * SCAN_TILE + tid * 4;
    int c[4];
    int s = 0;
#pragma unroll
    for (int i = 0; i < 4; ++i) {
        c[i] = (base + i < N_NODES) ? counts[base + i] : 0;
        s += c[i];
    }
    pre[tid] = s;
    __syncthreads();
    for (int off = 1; off < 256; off <<= 1) {
        int v = (tid >= off) ? pre[tid - off] : 0;
        __syncthreads();
        pre[tid] += v;
        __syncthreads();
    }
    int run = bpre[b] + pre[tid] - s;
#pragma unroll
    for (int i = 0; i < 4; ++i) {
        if (base + i < N_NODES) {
            offsets[base + i] = run;
            run += c[i];
        }
    }
}

__global__ void place_kernel(const int* __restrict__ src,
                             const int* __restrict__ dst,
                             const unsigned short* __restrict__ rank,
                             const int* __restrict__ offsets,
                             unsigned short* __restrict__ csr_src) {
    int e = blockIdx.x * blockDim.x + threadIdx.x;
    if (e >= N_EDGES) return;
    csr_src[offsets[dst[e]] + (int)rank[e]] = (unsigned short)src[e];
}

// ---------------------------------------------------------------------------
// weight repack: W[L][K][C] f32 -> frag-major bf16 P[L][KT][CT][64 lanes][8]
// lane l (li=l&15, hi=l>>4) gets W[kt*32 + hi*8 + j][ct*16 + li], j=0..7
// All three weight sets in ONE dispatch (launch-overhead removal).
// ---------------------------------------------------------------------------
template<int K, int C>
__device__ __forceinline__ void repack_one(const float* __restrict__ W,
                                           unsigned short* __restrict__ P, int t) {
    constexpr int KT = K / 32, CT = C / 16;
    int lane = t & 63; int rest = t >> 6;
    int ct = rest % CT; rest /= CT;
    int kt = rest % KT; int l = rest / KT;
    int li = lane & 15, hi = lane >> 4;
    const float* Wl = W + (size_t)l * K * C;
    short8v o;
#pragma unroll
    for (int j = 0; j < 8; ++j)
        o[j] = (short)f2bf(Wl[(size_t)(kt * 32 + hi * 8 + j) * C + ct * 16 + li]);
    *reinterpret_cast<short8v*>(P + ((size_t)l * KT * CT * 64 + (size_t)(kt * CT + ct) * 64 + lane) * 8) = o;
}

__global__ void repack_all_kernel(const float* __restrict__ W1, const float* __restrict__ W2,
                                  const float* __restrict__ W3,
                                  unsigned short* __restrict__ P1, unsigned short* __restrict__ P2,
                                  unsigned short* __restrict__ P3) {
    int t = blockIdx.x * 256 + threadIdx.x;       // 12288 total
    if (t < 3072)       repack_one<DIM, HID>(W1, P1, t);
    else if (t < 9216)  repack_one<HID, HID>(W2, P2, t - 3072);
    else                repack_one<HID, DIM>(W3, P3, t - 9216);
}

// ---------------------------------------------------------------------------
// fused GIN layer (r13 gather + r14 fused pooling on the last layer).
// Gather: per node, TWO groups of 8 lanes walk static halves of the edge
// list (flat unroll-4; 16 B loads). Halves -> two f32 LDS tiles (no atomics).
// MLP: MFMA W1 -> tanh -> xpose -> W2 -> tanh -> xpose -> W3 -> tanh(tanh).
// LAST layer: output feeds ONLY the mean-pool, so skip the global x write
// and atomicAdd run-compressed f32 partials into psums (32 KB, L2-resident).
// IN/OUT ping-pong (round-6 race). Frag conv: k = kt*32+hi*8+j, row/col=li.
// D conv (m89): col=li, row=hi*4+j. tileA/B swizzle byte^=(row&7)<<4.
// agg tiles stride 68 floats.
// ---------------------------------------------------------------------------
template<bool F32IN, bool LAST>
__global__ __launch_bounds__(256) void gnn_layer_kernel(
        const float* __restrict__ xf, const unsigned short* __restrict__ xb,
        const int* __restrict__ offsets, const unsigned short* __restrict__ csr_src,
        const unsigned short* __restrict__ pw1, const float* __restrict__ bias1,
        const unsigned short* __restrict__ pw2, const float* __restrict__ bias2,
        const unsigned short* __restrict__ pw3, const float* __restrict__ bias3,
        unsigned short* __restrict__ outx,
        const int* __restrict__ batch, float* __restrict__ psums) {
    __shared__ float aggA[16 * 68];              // 4.25 KB, half 0 (+self)
    __shared__ float aggB[16 * 68];              // 4.25 KB, half 1
    __shared__ unsigned short tileA[16 * 128];   // 4 KB
    __shared__ unsigned short tileB[16 * 128];   // 4 KB
    __shared__ int soff[17];
    const int tid = threadIdx.x;
    const int wave = tid >> 6, lane = tid & 63;
    const int li = lane & 15, hi = lane >> 4;
    const int r0 = blockIdx.x * 16;              // 3125*16 == N exactly
    char* tA = reinterpret_cast<char*>(tileA);
    char* tB = reinterpret_cast<char*>(tileB);

    if (tid < 17) soff[tid] = offsets[r0 + tid];
    __syncthreads();

    // ---- gather: group = 8 lanes; node nr = group>>1, half h = group&1 ----
    {
        const int g  = tid >> 3;                 // 0..31
        const int nr = g >> 1;                   // node row 0..15
        const int h  = g & 1;
        const int q  = tid & 7;                  // channel oct (8 ch, 16 B)
        const int n  = r0 + nr;
        float a[8];
        if (h == 0) {                            // seed with self row
            if (F32IN) {
                const float* xr = xf + (size_t)n * DIM + q * 8;
                float4 u = *reinterpret_cast<const float4*>(xr);
                float4 w = *reinterpret_cast<const float4*>(xr + 4);
                a[0]=u.x; a[1]=u.y; a[2]=u.z; a[3]=u.w;
                a[4]=w.x; a[5]=w.y; a[6]=w.z; a[7]=w.w;
            } else {
                short8v v = *reinterpret_cast<const short8v*>(xb + (size_t)n * DIM + q * 8);
#pragma unroll
                for (int j = 0; j < 8; ++j) a[j] = bf2f((unsigned short)v[j]);
            }
        } else {
#pragma unroll
            for (int j = 0; j < 8; ++j) a[j] = 0.f;
        }
        const int p0 = soff[nr], pe1 = soff[nr + 1];
        const int mid = p0 + ((pe1 - p0 + 1) >> 1);
        int p        = h ? mid : p0;
        const int pe = h ? pe1 : mid;
        for (; p + 4 <= pe; p += 4) {
            int s0 = csr_src[p + 0];
            int s1 = csr_src[p + 1];
            int s2 = csr_src[p + 2];
            int s3 = csr_src[p + 3];
            if (F32IN) {
                const float* x0 = xf + (size_t)s0 * DIM + q * 8;
                const float* x1 = xf + (size_t)s1 * DIM + q * 8;
                const float* x2 = xf + (size_t)s2 * DIM + q * 8;
                const float* x3 = xf + (size_t)s3 * DIM + q * 8;
                float4 u0 = *reinterpret_cast<const float4*>(x0);
                float4 w0 = *reinterpret_cast<const float4*>(x0 + 4);
                float4 u1 = *reinterpret_cast<const float4*>(x1);
                float4 w1 = *reinterpret_cast<const float4*>(x1 + 4);
                float4 u2 = *reinterpret_cast<const float4*>(x2);
                float4 w2 = *reinterpret_cast<const float4*>(x2 + 4);
                float4 u3 = *reinterpret_cast<const float4*>(x3);
                float4 w3 = *reinterpret_cast<const float4*>(x3 + 4);
                a[0] += u0.x + u1.x + u2.x + u3.x;
                a[1] += u0.y + u1.y + u2.y + u3.y;
                a[2] += u0.z + u1.z + u2.z + u3.z;
                a[3] += u0.w + u1.w + u2.w + u3.w;
                a[4] += w0.x + w1.x + w2.x + w3.x;
                a[5] += w0.y + w1.y + w2.y + w3.y;
                a[6] += w0.z + w1.z + w2.z + w3.z;
                a[7] += w0.w + w1.w + w2.w + w3.w;
            } else {
                short8v v0 = *reinterpret_cast<const short8v*>(xb + (size_t)s0 * DIM + q * 8);
                short8v v1 = *reinterpret_cast<const short8v*>(xb + (size_t)s1 * DIM + q * 8);
                short8v v2 = *reinterpret_cast<const short8v*>(xb + (size_t)s2 * DIM + q * 8);
                short8v v3 = *reinterpret_cast<const short8v*>(xb + (size_t)s3 * DIM + q * 8);
#pragma unroll
                for (int j = 0; j < 8; ++j)
                    a[j] += bf2f((unsigned short)v0[j]) + bf2f((unsigned short)v1[j])
                          + bf2f((unsigned short)v2[j]) + bf2f((unsigned short)v3[j]);
            }
        }
        for (; p < pe; ++p) {
            int s = csr_src[p];
            if (F32IN) {
                const float* xs = xf + (size_t)s * DIM + q * 8;
                float4 u = *reinterpret_cast<const float4*>(xs);
                float4 w = *reinterpret_cast<const float4*>(xs + 4);
                a[0] += u.x; a[1] += u.y; a[2] += u.z; a[3] += u.w;
                a[4] += w.x; a[5] += w.y; a[6] += w.z; a[7] += w.w;
            } else {
                short8v v = *reinterpret_cast<const short8v*>(xb + (size_t)s * DIM + q * 8);
#pragma unroll
                for (int j = 0; j < 8; ++j) a[j] += bf2f((unsigned short)v[j]);
            }
        }
        float* d = (h ? aggB : aggA) + nr * 68 + q * 8;
        *reinterpret_cast<f32x4*>(d)     = (f32x4){a[0], a[1], a[2], a[3]};
        *reinterpret_cast<f32x4*>(d + 4) = (f32x4){a[4], a[5], a[6], a[7]};
    }
    __syncthreads();

    // ---- A-frags: sum the two halves (row = li, k = kt*32 + hi*8 + j) ----
    short8v af[2];
#pragma unroll
    for (int kt = 0; kt < 2; ++kt) {
        const float* sA = &aggA[li * 68 + kt * 32 + hi * 8];
        const float* sB = &aggB[li * 68 + kt * 32 + hi * 8];
#pragma unroll
        for (int j = 0; j < 8; ++j) af[kt][j] = (short)f2bf(sA[j] + sB[j]);
    }

    // ---- gemm1: K=64, C=128; wave owns ct = 2*wave + {0,1} ----
    f32x4 acc1[2];
#pragma unroll
    for (int c = 0; c < 2; ++c) acc1[c] = (f32x4){0.f, 0.f, 0.f, 0.f};
#pragma unroll
    for (int c = 0; c < 2; ++c) {
        const int ct = 2 * wave + c;
#pragma unroll
        for (int kt = 0; kt < 2; ++kt) {
            short8v bfr = *reinterpret_cast<const short8v*>(pw1 + ((size_t)(kt * 8 + ct) * 64 + lane) * 8);
            acc1[c] = __builtin_amdgcn_mfma_f32_16x16x32_bf16(af[kt], bfr, acc1[c], 0, 0, 0);
        }
    }
#pragma unroll
    for (int c = 0; c < 2; ++c) {
        const int ct = 2 * wave + c;
        float bv = bias1[ct * 16 + li];
#pragma unroll
        for (int j = 0; j < 4; ++j) {
            int row = hi * 4 + j;
            unsigned off = (unsigned)(row * 256 + (ct * 16 + li) * 2) ^ ((unsigned)(row & 7) << 4);
            *reinterpret_cast<unsigned short*>(tA + off) = f2bf(fast_tanh(acc1[c][j] + bv));
        }
    }
    __syncthreads();

    // ---- gemm2: K=128, C=128 ----
    short8v af2[4];
#pragma unroll
    for (int kt = 0; kt < 4; ++kt) {
        unsigned off = (unsigned)(li * 256 + (kt * 32 + hi * 8) * 2) ^ ((unsigned)(li & 7) << 4);
        af2[kt] = *reinterpret_cast<const short8v*>(tA + off);
    }
    f32x4 acc2[2];
#pragma unroll
    for (int c = 0; c < 2; ++c) acc2[c] = (f32x4){0.f, 0.f, 0.f, 0.f};
#pragma unroll
    for (int c = 0; c < 2; ++c) {
        const int ct = 2 * wave + c;
#pragma unroll
        for (int kt = 0; kt < 4; ++kt) {
            short8v bfr = *reinterpret_cast<const short8v*>(pw2 + ((size_t)(kt * 8 + ct) * 64 + lane) * 8);
            acc2[c] = __builtin_amdgcn_mfma_f32_16x16x32_bf16(af2[kt], bfr, acc2[c], 0, 0, 0);
        }
    }
#pragma unroll
    for (int c = 0; c < 2; ++c) {
        const int ct = 2 * wave + c;
        float bv = bias2[ct * 16 + li];
#pragma unroll
        for (int j = 0; j < 4; ++j) {
            int row = hi * 4 + j;
            unsigned off = (unsigned)(row * 256 + (ct * 16 + li) * 2) ^ ((unsigned)(row & 7) << 4);
            *reinterpret_cast<unsigned short*>(tB + off) = f2bf(fast_tanh(acc2[c][j] + bv));
        }
    }
    __syncthreads();

    // ---- gemm3: K=128, C=64; wave owns ct = wave ----
    short8v af3[4];
#pragma unroll
    for (int kt = 0; kt < 4; ++kt) {
        unsigned off = (unsigned)(li * 256 + (kt * 32 + hi * 8) * 2) ^ ((unsigned)(li & 7) << 4);
        af3[kt] = *reinterpret_cast<const short8v*>(tB + off);
    }
    f32x4 acc3 = (f32x4){0.f, 0.f, 0.f, 0.f};
#pragma unroll
    for (int kt = 0; kt < 4; ++kt) {
        short8v bfr = *reinterpret_cast<const short8v*>(pw3 + ((size_t)(kt * 4 + wave) * 64 + lane) * 8);
        acc3 = __builtin_amdgcn_mfma_f32_16x16x32_bf16(af3[kt], bfr, acc3, 0, 0, 0);
    }
    {
        const int c = wave * 16 + li;
        float bv = bias3[c];
        if (LAST) {
            // fused mean-pool partial: run-compress the 4 consecutive rows
            // (batch sorted) and atomicAdd f32 partials into psums[g][c].
            const int row0 = r0 + hi * 4;
            float v[4];
#pragma unroll
            for (int j = 0; j < 4; ++j) v[j] = fast_tanh(fast_tanh(acc3[j] + bv));
            int g = batch[row0];
            float acc = v[0];
#pragma unroll
            for (int j = 1; j < 4; ++j) {
                int gj = batch[row0 + j];
                if (gj == g) acc += v[j];
                else {
                    atomicAdd(&psums[g * DIM + c], acc);
                    g = gj; acc = v[j];
                }
            }
            atomicAdd(&psums[g * DIM + c], acc);
        } else {
#pragma unroll
            for (int j = 0; j < 4; ++j) {
                int row = r0 + hi * 4 + j;
                float vv = fast_tanh(fast_tanh(acc3[j] + bv));
                outx[(size_t)row * DIM + c] = f2bf(vv);
            }
        }
    }
}

// out[g][d] = psums[g][d] / count(g); count via binary search (batch sorted)
__global__ void pool_final_kernel(const float* __restrict__ sums,
                                  const int* __restrict__ batch,
                                  float* __restrict__ out) {
    const int g = blockIdx.x;
    const int d = threadIdx.x;
    int lo = 0, hi = N_NODES;
    while (lo < hi) { int m = (lo + hi) >> 1; if (batch[m] < g) lo = m + 1; else hi = m; }
    int start = lo;
    hi = N_NODES;
    while (lo < hi) { int m = (lo + hi) >> 1; if (batch[m] < g + 1) lo = m + 1; else hi = m; }
    float cnt = (float)(lo - start);
    out[g * DIM + d] = sums[g * DIM + d] / fmaxf(cnt, 1.f);
}

// ---------------------------------------------------------------------------
extern "C" void kernel_launch(void* const* d_in, const int* in_sizes, int n_in,
                              void* d_out, int out_size, void* d_ws, size_t ws_size,
                              hipStream_t stream) {
    const float* attrs = (const float*)d_in[0];
    const float* W1    = (const float*)d_in[1];
    const float* b1    = (const float*)d_in[2];
    const float* W2    = (const float*)d_in[3];
    const float* b2    = (const float*)d_in[4];
    const float* W3    = (const float*)d_in[5];
    const float* b3    = (const float*)d_in[6];
    const int* edge_index = (const int*)d_in[7];
    const int* batch      = (const int*)d_in[8];
    float* out = (float*)d_out;

    unsigned short* buf0 = (unsigned short*)d_ws;               // N*64 bf16
    unsigned short* buf1 = buf0 + (size_t)N_NODES * DIM;        // N*64 bf16
    unsigned short* pW1  = buf1 + (size_t)N_NODES * DIM;        // 24576
    unsigned short* pW2  = pW1 + 24576;                         // 49152
    unsigned short* pW3  = pW2 + 49152;                         // 24576
    float* psums  = (float*)(pW3 + 24576);                      // G*64 f32
    int* offsets  = (int*)(psums + NGRAPH * DIM);               // N+1
    unsigned short* csr16 = (unsigned short*)(offsets + N_NODES + 1);  // E u16
    unsigned short* rank  = csr16 + N_EDGES;                    // E u16
    int* counts   = (int*)(rank + N_EDGES);                     // N
    int* bsum     = counts + N_NODES;                           // SCAN_NB
    int* bpre     = bsum + SCAN_NB;                             // SCAN_NB

    const int* src = edge_index;
    const int* dst = edge_index + N_EDGES;

    const int edge_blocks  = (N_EDGES + 255) / 256;
    const int count_blocks = (N_EDGES / 2 + 255) / 256;
    const int gnn_blocks   = N_NODES / 16;                      // 3125, exact

    // ---- CSR build (once; edge list is layer-invariant) ----
    hipMemsetAsync(counts, 0, (size_t)N_NODES * sizeof(int), stream);
    hipMemsetAsync(psums, 0, (size_t)NGRAPH * DIM * sizeof(float), stream);
    count_kernel<<<count_blocks, 256, 0, stream>>>(dst, counts, rank);
    scan_partial_kernel<<<SCAN_NB, 256, 0, stream>>>(counts, bsum);
    scan_mid_kernel<<<1, 64, 0, stream>>>(bsum, bpre, offsets);
    scan_final_kernel<<<SCAN_NB, 256, 0, stream>>>(counts, bpre, offsets);
    place_kernel<<<edge_blocks, 256, 0, stream>>>(src, dst, rank, offsets, csr16);

    // ---- weight repack to frag-major bf16 (one dispatch) ----
    repack_all_kernel<<<48, 256, 0, stream>>>(W1, W2, W3, pW1, pW2, pW3);

    // ---- fused layers: attrs -> buf0 -> buf1 -> psums (pool fused) ----
    for (int l = 0; l < LAYERS; ++l) {
        const unsigned short* w1 = pW1 + (size_t)l * 2 * 8 * 64 * 8;
        const unsigned short* w2 = pW2 + (size_t)l * 4 * 8 * 64 * 8;
        const unsigned short* w3 = pW3 + (size_t)l * 4 * 4 * 64 * 8;
        const float* bb1 = b1 + (size_t)l * HID;
        const float* bb2 = b2 + (size_t)l * HID;
        const float* bb3 = b3 + (size_t)l * DIM;
        if (l == 0)
            gnn_layer_kernel<true, false><<<gnn_blocks, 256, 0, stream>>>(
                attrs, nullptr, offsets, csr16, w1, bb1, w2, bb2, w3, bb3,
                buf0, nullptr, nullptr);
        else if (l == 1)
            gnn_layer_kernel<false, false><<<gnn_blocks, 256, 0, stream>>>(
                nullptr, buf0, offsets, csr16, w1, bb1, w2, bb2, w3, bb3,
                buf1, nullptr, nullptr);
        else
            gnn_layer_kernel<false, true><<<gnn_blocks, 256, 0, stream>>>(
                nullptr, buf1, offsets, csr16, w1, bb1, w2, bb2, w3, bb3,
                nullptr, batch, psums);
    }

    // ---- finalize mean pool ----
    pool_final_kernel<<<NGRAPH, DIM, 0, stream>>>(psums, batch, out);
}